// Round 1
// baseline (349.396 us; speedup 1.0000x reference)
//
#include <hip/hip_runtime.h>
#include <hip/hip_bf16.h>

typedef unsigned short u16;
typedef __attribute__((ext_vector_type(4))) float f32x4;
typedef __attribute__((ext_vector_type(8))) short short8;

#define SEQ 2048
#define FD  1024
#define NH  16
#define DHD 64

__device__ __forceinline__ u16 f2bf(float f) {
  __hip_bfloat16 h = __float2bfloat16(f);
  return *reinterpret_cast<u16*>(&h);
}

// ---- shared GEMM body: 128x128 tile of C = A[M,K] * B[N,K]^T (K-major both),
// bf16 MFMA 16x16x32, fp32 accum. A/B staged (with fp32->bf16 cvt if needed).
template <typename TA, typename TB>
__device__ __forceinline__ void gemm_bt_body(const TA* __restrict__ A, const TB* __restrict__ Bm,
                                             int m0, int n0, u16* As, u16* Bs, f32x4 acc[4][4]) {
  const int tid = threadIdx.x;
  const int lane = tid & 63;
  const int wr = (tid >> 7) & 1;   // wave row quadrant
  const int wc = (tid >> 6) & 1;   // wave col quadrant
  const int lr = lane & 15;
  const int lk = (lane >> 4) << 3;
#pragma unroll
  for (int m = 0; m < 4; ++m)
#pragma unroll
    for (int n = 0; n < 4; ++n) acc[m][n] = {0.f, 0.f, 0.f, 0.f};

  const int r_ = tid >> 2;
  const int c_ = (tid & 3) << 3;

  for (int k0 = 0; k0 < FD; k0 += 32) {
    __syncthreads();
#pragma unroll
    for (int c = 0; c < 2; ++c) {   // stage A tile half (64 rows x 32 cols)
      int r = c * 64 + r_;
      const TA* s = A + (size_t)(m0 + r) * FD + k0 + c_;
      short8 o;
      if constexpr (sizeof(TA) == 4) {
        f32x4 v0 = *reinterpret_cast<const f32x4*>(s);
        f32x4 v1 = *reinterpret_cast<const f32x4*>(s + 4);
#pragma unroll
        for (int j = 0; j < 4; ++j) { o[j] = (short)f2bf(v0[j]); o[4 + j] = (short)f2bf(v1[j]); }
      } else {
        o = *reinterpret_cast<const short8*>(s);
      }
      *reinterpret_cast<short8*>(&As[r * 32 + c_]) = o;
    }
#pragma unroll
    for (int c = 0; c < 2; ++c) {   // stage B tile half
      int r = c * 64 + r_;
      const TB* s = Bm + (size_t)(n0 + r) * FD + k0 + c_;
      short8 o;
      if constexpr (sizeof(TB) == 4) {
        f32x4 v0 = *reinterpret_cast<const f32x4*>(s);
        f32x4 v1 = *reinterpret_cast<const f32x4*>(s + 4);
#pragma unroll
        for (int j = 0; j < 4; ++j) { o[j] = (short)f2bf(v0[j]); o[4 + j] = (short)f2bf(v1[j]); }
      } else {
        o = *reinterpret_cast<const short8*>(s);
      }
      *reinterpret_cast<short8*>(&Bs[r * 32 + c_]) = o;
    }
    __syncthreads();

    short8 a[4], b[4];
#pragma unroll
    for (int m = 0; m < 4; ++m)
      a[m] = *reinterpret_cast<const short8*>(&As[(wr * 64 + m * 16 + lr) * 32 + lk]);
#pragma unroll
    for (int n = 0; n < 4; ++n)
      b[n] = *reinterpret_cast<const short8*>(&Bs[(wc * 64 + n * 16 + lr) * 32 + lk]);
#pragma unroll
    for (int m = 0; m < 4; ++m)
#pragma unroll
      for (int n = 0; n < 4; ++n)
        acc[m][n] = __builtin_amdgcn_mfma_f32_16x16x32_bf16(a[m], b[n], acc[m][n], 0, 0, 0);
  }
}

// ---- fused QKV projection: z selects which of Q/K/V. q,k -> [B,H,S,DH] bf16; v -> [B,H,DH,S] bf16
__global__ __launch_bounds__(256) void proj_qkv_kernel(
    const float* __restrict__ Q, const float* __restrict__ K, const float* __restrict__ V,
    const float* __restrict__ Wq, const float* __restrict__ Wk, const float* __restrict__ Wv,
    const float* __restrict__ bq, const float* __restrict__ bk, const float* __restrict__ bv,
    u16* __restrict__ qh, u16* __restrict__ kh, u16* __restrict__ vT) {
  __shared__ u16 As[128 * 32];
  __shared__ u16 Bs[128 * 32];
  const int which = blockIdx.z;
  const float* A    = (which == 0) ? Q  : (which == 1) ? K  : V;
  const float* W    = (which == 0) ? Wq : (which == 1) ? Wk : Wv;
  const float* bias = (which == 0) ? bq : (which == 1) ? bk : bv;
  u16* out          = (which == 0) ? qh : (which == 1) ? kh : vT;
  const int m0 = blockIdx.y * 128, n0 = blockIdx.x * 128;

  f32x4 acc[4][4];
  gemm_bt_body(A, W, m0, n0, As, Bs, acc);

  const int lane = threadIdx.x & 63;
  const int wr = (threadIdx.x >> 7) & 1, wc = (threadIdx.x >> 6) & 1;
  const int rbase = m0 + wr * 64 + ((lane >> 4) << 2);
  const int cbase = n0 + wc * 64 + (lane & 15);
#pragma unroll
  for (int n = 0; n < 4; ++n) {
    const int col = cbase + n * 16;
    const float bvv = bias[col];
    const int h = col >> 6, dh = col & 63;
#pragma unroll
    for (int m = 0; m < 4; ++m) {
#pragma unroll
      for (int r = 0; r < 4; ++r) {
        const int row = rbase + m * 16 + r;
        const int b = row >> 11, s = row & 2047;
        const float v = acc[m][n][r] + bvv;
        size_t idx;
        if (which < 2) idx = ((size_t)((b * 16 + h) * 2048 + s)) * 64 + dh;   // [B,H,S,DH]
        else           idx = ((size_t)((b * 16 + h) * 64 + dh)) * 2048 + s;   // [B,H,DH,S]
        out[idx] = f2bf(v);
      }
    }
  }
}

// ---- flash attention: 4 independent waves/block, 16 q-rows/wave, KVBLK=64
__global__ __launch_bounds__(256) void attn_kernel(
    const u16* __restrict__ qh, const u16* __restrict__ kh, const u16* __restrict__ vT,
    const float* __restrict__ mask, u16* __restrict__ O) {
  __shared__ u16 P[4][16][72];   // per-wave P bounce, +8 pad -> 2-way (free) conflicts
  const int wave = threadIdx.x >> 6, lane = threadIdx.x & 63;
  const int bh = blockIdx.x >> 5;
  const int q0 = (blockIdx.x & 31) * 64 + wave * 16;
  const u16* qp = qh + (size_t)bh * SEQ * DHD;
  const u16* kp = kh + (size_t)bh * SEQ * DHD;
  const u16* vp = vT + (size_t)bh * DHD * SEQ;
  const int lr = lane & 15, lg = lane >> 4;
  const float LOG2E = 1.44269504088896340736f;

  short8 aq[2];
#pragma unroll
  for (int kk = 0; kk < 2; ++kk)
    aq[kk] = *reinterpret_cast<const short8*>(&qp[(size_t)(q0 + lr) * DHD + kk * 32 + lg * 8]);

  float mrow[4], lrow[4];
  f32x4 oacc[4];
#pragma unroll
  for (int r = 0; r < 4; ++r) { mrow[r] = -INFINITY; lrow[r] = 0.f; }
#pragma unroll
  for (int nf = 0; nf < 4; ++nf) oacc[nf] = {0.f, 0.f, 0.f, 0.f};

  for (int kv0 = 0; kv0 < SEQ; kv0 += 64) {
    // S = Q K^T  (16 q-rows x 64 kv-cols)
    f32x4 sf[4];
#pragma unroll
    for (int kf = 0; kf < 4; ++kf) {
      f32x4 z = {0.f, 0.f, 0.f, 0.f};
#pragma unroll
      for (int kk = 0; kk < 2; ++kk) {
        short8 bk_ = *reinterpret_cast<const short8*>(&kp[(size_t)(kv0 + kf * 16 + lr) * DHD + kk * 32 + lg * 8]);
        z = __builtin_amdgcn_mfma_f32_16x16x32_bf16(aq[kk], bk_, z, 0, 0, 0);
      }
      sf[kf] = z;
    }
    // scale + mask, tile row-max
    float mt[4] = {-INFINITY, -INFINITY, -INFINITY, -INFINITY};
#pragma unroll
    for (int kf = 0; kf < 4; ++kf)
#pragma unroll
      for (int r = 0; r < 4; ++r) {
        const int qs = q0 + lg * 4 + r;
        const int ks = kv0 + kf * 16 + lr;
        float sc = sf[kf][r] * 0.125f + mask[(size_t)qs * SEQ + ks];
        sf[kf][r] = sc;
        mt[r] = fmaxf(mt[r], sc);
      }
#pragma unroll
    for (int off = 8; off >= 1; off >>= 1)
#pragma unroll
      for (int r = 0; r < 4; ++r) mt[r] = fmaxf(mt[r], __shfl_xor(mt[r], off));

    float al[4], psum[4];
#pragma unroll
    for (int r = 0; r < 4; ++r) {
      const float mn = fmaxf(mrow[r], mt[r]);
      al[r] = exp2f((mrow[r] - mn) * LOG2E);
      mrow[r] = mn;
      psum[r] = 0.f;
    }
#pragma unroll
    for (int kf = 0; kf < 4; ++kf)
#pragma unroll
      for (int r = 0; r < 4; ++r) {
        const float p = exp2f((sf[kf][r] - mrow[r]) * LOG2E);
        psum[r] += p;
        P[wave][lg * 4 + r][kf * 16 + lr] = f2bf(p);
      }
#pragma unroll
    for (int off = 8; off >= 1; off >>= 1)
#pragma unroll
      for (int r = 0; r < 4; ++r) psum[r] += __shfl_xor(psum[r], off);
#pragma unroll
    for (int r = 0; r < 4; ++r) lrow[r] = lrow[r] * al[r] + psum[r];
#pragma unroll
    for (int nf = 0; nf < 4; ++nf)
#pragma unroll
      for (int r = 0; r < 4; ++r) oacc[nf][r] *= al[r];

    // O += P V   (same-wave LDS write->read: compiler inserts lgkmcnt waits)
#pragma unroll
    for (int ks = 0; ks < 2; ++ks) {
      short8 ap = *reinterpret_cast<const short8*>(&P[wave][lr][ks * 32 + lg * 8]);
#pragma unroll
      for (int nf = 0; nf < 4; ++nf) {
        short8 bv_ = *reinterpret_cast<const short8*>(&vp[(size_t)(nf * 16 + lr) * SEQ + kv0 + ks * 32 + lg * 8]);
        oacc[nf] = __builtin_amdgcn_mfma_f32_16x16x32_bf16(ap, bv_, oacc[nf], 0, 0, 0);
      }
    }
  }
  // epilogue: O in [B,S,H,DH] (= [B,S,F]) bf16
  const int b = bh >> 4, h = bh & 15;
#pragma unroll
  for (int nf = 0; nf < 4; ++nf)
#pragma unroll
    for (int r = 0; r < 4; ++r) {
      const int s = q0 + lg * 4 + r;
      const int vd = nf * 16 + lr;
      const float o = oacc[nf][r] / lrow[r];
      O[((size_t)(b * SEQ + s) * NH + h) * DHD + vd] = f2bf(o);
    }
}

// ---- output projection: d_out = O @ Wo^T + bo (fp32 out)
__global__ __launch_bounds__(256) void out_proj_kernel(
    const u16* __restrict__ O, const float* __restrict__ Wo, const float* __restrict__ bo,
    float* __restrict__ out) {
  __shared__ u16 As[128 * 32];
  __shared__ u16 Bs[128 * 32];
  const int m0 = blockIdx.y * 128, n0 = blockIdx.x * 128;
  f32x4 acc[4][4];
  gemm_bt_body(O, Wo, m0, n0, As, Bs, acc);

  const int lane = threadIdx.x & 63;
  const int wr = (threadIdx.x >> 7) & 1, wc = (threadIdx.x >> 6) & 1;
  const int rbase = m0 + wr * 64 + ((lane >> 4) << 2);
  const int cbase = n0 + wc * 64 + (lane & 15);
#pragma unroll
  for (int n = 0; n < 4; ++n) {
    const int col = cbase + n * 16;
    const float bvv = bo[col];
#pragma unroll
    for (int m = 0; m < 4; ++m)
#pragma unroll
      for (int r = 0; r < 4; ++r) {
        const int row = rbase + m * 16 + r;
        out[(size_t)row * FD + col] = acc[m][n][r] + bvv;
      }
  }
}

extern "C" void kernel_launch(void* const* d_in, const int* in_sizes, int n_in,
                              void* d_out, int out_size, void* d_ws, size_t ws_size,
                              hipStream_t stream) {
  (void)in_sizes; (void)n_in; (void)out_size; (void)ws_size;
  const float* Q    = (const float*)d_in[0];
  const float* K    = (const float*)d_in[1];
  const float* V    = (const float*)d_in[2];
  const float* mask = (const float*)d_in[3];
  const float* Wq   = (const float*)d_in[4];
  const float* bq   = (const float*)d_in[5];
  const float* Wk   = (const float*)d_in[6];
  const float* bk   = (const float*)d_in[7];
  const float* Wv   = (const float*)d_in[8];
  const float* bv   = (const float*)d_in[9];
  const float* Wo   = (const float*)d_in[10];
  const float* bo   = (const float*)d_in[11];
  float* out = (float*)d_out;

  u16* ws = (u16*)d_ws;
  const size_t SZ = (size_t)4096 * 1024;   // B*S*F elements
  u16* qh = ws;            // [B,H,S,DH] bf16
  u16* kh = qh + SZ;       // [B,H,S,DH] bf16
  u16* vT = kh + SZ;       // [B,H,DH,S] bf16
  u16* O  = vT + SZ;       // [B,S,H,DH] bf16

  dim3 gproj(FD / 128, (2 * SEQ) / 128, 3);      // (8, 32, 3)
  proj_qkv_kernel<<<gproj, 256, 0, stream>>>(Q, K, V, Wq, Wk, Wv, bq, bk, bv, qh, kh, vT);

  attn_kernel<<<dim3((2 * NH) * (SEQ / 64)), 256, 0, stream>>>(qh, kh, vT, mask, O);

  out_proj_kernel<<<dim3(FD / 128, (2 * SEQ) / 128), 256, 0, stream>>>(O, Wo, bo, out);
}

// Round 2
// 280.803 us; speedup vs baseline: 1.2443x; 1.2443x over previous
//
#include <hip/hip_runtime.h>
#include <hip/hip_bf16.h>

typedef unsigned short u16;
typedef unsigned int u32;
typedef __attribute__((ext_vector_type(4))) float f32x4;
typedef __attribute__((ext_vector_type(16))) float f32x16;
typedef __attribute__((ext_vector_type(8))) short short8;

#define SEQ 2048
#define FD  1024
#define NH  16
#define DHD 64

__device__ __forceinline__ u16 f2bf(float f) {
  __hip_bfloat16 h = __float2bfloat16(f);
  return *reinterpret_cast<u16*>(&h);
}
__device__ __forceinline__ u32 pack2bf(float lo, float hi) {
  return (u32)f2bf(lo) | ((u32)f2bf(hi) << 16);
}

// ---- shared GEMM body: 128x128 tile of C = A[M,K] * B[N,K]^T (K-major both),
// bf16 MFMA 16x16x32, fp32 accum. A/B staged (with fp32->bf16 cvt if needed).
template <typename TA, typename TB>
__device__ __forceinline__ void gemm_bt_body(const TA* __restrict__ A, const TB* __restrict__ Bm,
                                             int m0, int n0, u16* As, u16* Bs, f32x4 acc[4][4]) {
  const int tid = threadIdx.x;
  const int lane = tid & 63;
  const int wr = (tid >> 7) & 1;   // wave row quadrant
  const int wc = (tid >> 6) & 1;   // wave col quadrant
  const int lr = lane & 15;
  const int lk = (lane >> 4) << 3;
#pragma unroll
  for (int m = 0; m < 4; ++m)
#pragma unroll
    for (int n = 0; n < 4; ++n) acc[m][n] = {0.f, 0.f, 0.f, 0.f};

  const int r_ = tid >> 2;
  const int c_ = (tid & 3) << 3;

  for (int k0 = 0; k0 < FD; k0 += 32) {
    __syncthreads();
#pragma unroll
    for (int c = 0; c < 2; ++c) {   // stage A tile half (64 rows x 32 cols)
      int r = c * 64 + r_;
      const TA* s = A + (size_t)(m0 + r) * FD + k0 + c_;
      short8 o;
      if constexpr (sizeof(TA) == 4) {
        f32x4 v0 = *reinterpret_cast<const f32x4*>(s);
        f32x4 v1 = *reinterpret_cast<const f32x4*>(s + 4);
#pragma unroll
        for (int j = 0; j < 4; ++j) { o[j] = (short)f2bf(v0[j]); o[4 + j] = (short)f2bf(v1[j]); }
      } else {
        o = *reinterpret_cast<const short8*>(s);
      }
      *reinterpret_cast<short8*>(&As[r * 32 + c_]) = o;
    }
#pragma unroll
    for (int c = 0; c < 2; ++c) {   // stage B tile half
      int r = c * 64 + r_;
      const TB* s = Bm + (size_t)(n0 + r) * FD + k0 + c_;
      short8 o;
      if constexpr (sizeof(TB) == 4) {
        f32x4 v0 = *reinterpret_cast<const f32x4*>(s);
        f32x4 v1 = *reinterpret_cast<const f32x4*>(s + 4);
#pragma unroll
        for (int j = 0; j < 4; ++j) { o[j] = (short)f2bf(v0[j]); o[4 + j] = (short)f2bf(v1[j]); }
      } else {
        o = *reinterpret_cast<const short8*>(s);
      }
      *reinterpret_cast<short8*>(&Bs[r * 32 + c_]) = o;
    }
    __syncthreads();

    short8 a[4], b[4];
#pragma unroll
    for (int m = 0; m < 4; ++m)
      a[m] = *reinterpret_cast<const short8*>(&As[(wr * 64 + m * 16 + lr) * 32 + lk]);
#pragma unroll
    for (int n = 0; n < 4; ++n)
      b[n] = *reinterpret_cast<const short8*>(&Bs[(wc * 64 + n * 16 + lr) * 32 + lk]);
#pragma unroll
    for (int m = 0; m < 4; ++m)
#pragma unroll
      for (int n = 0; n < 4; ++n)
        acc[m][n] = __builtin_amdgcn_mfma_f32_16x16x32_bf16(a[m], b[n], acc[m][n], 0, 0, 0);
  }
}

// ---- fused QKV projection: z selects which of Q/K/V. q,k -> [B,H,S,DH] bf16; v -> [B,H,DH,S] bf16
// q is pre-scaled by (1/sqrt(DH))*log2(e) so attention works in exp2 domain.
__global__ __launch_bounds__(256) void proj_qkv_kernel(
    const float* __restrict__ Q, const float* __restrict__ K, const float* __restrict__ V,
    const float* __restrict__ Wq, const float* __restrict__ Wk, const float* __restrict__ Wv,
    const float* __restrict__ bq, const float* __restrict__ bk, const float* __restrict__ bv,
    u16* __restrict__ qh, u16* __restrict__ kh, u16* __restrict__ vT) {
  __shared__ u16 As[128 * 32];
  __shared__ u16 Bs[128 * 32];
  const int which = blockIdx.z;
  const float* A    = (which == 0) ? Q  : (which == 1) ? K  : V;
  const float* W    = (which == 0) ? Wq : (which == 1) ? Wk : Wv;
  const float* bias = (which == 0) ? bq : (which == 1) ? bk : bv;
  u16* out          = (which == 0) ? qh : (which == 1) ? kh : vT;
  const int m0 = blockIdx.y * 128, n0 = blockIdx.x * 128;
  const float qscale = 0.18033688011112042f;  // (1/8) * log2(e)

  f32x4 acc[4][4];
  gemm_bt_body(A, W, m0, n0, As, Bs, acc);

  const int lane = threadIdx.x & 63;
  const int wr = (threadIdx.x >> 7) & 1, wc = (threadIdx.x >> 6) & 1;
  const int rbase = m0 + wr * 64 + ((lane >> 4) << 2);
  const int cbase = n0 + wc * 64 + (lane & 15);
#pragma unroll
  for (int n = 0; n < 4; ++n) {
    const int col = cbase + n * 16;
    const float bvv = bias[col];
    const int h = col >> 6, dh = col & 63;
#pragma unroll
    for (int m = 0; m < 4; ++m) {
#pragma unroll
      for (int r = 0; r < 4; ++r) {
        const int row = rbase + m * 16 + r;
        const int b = row >> 11, s = row & 2047;
        float v = acc[m][n][r] + bvv;
        if (which == 0) v *= qscale;
        size_t idx;
        if (which < 2) idx = ((size_t)((b * 16 + h) * 2048 + s)) * 64 + dh;   // [B,H,S,DH]
        else           idx = ((size_t)((b * 16 + h) * 64 + dh)) * 2048 + s;   // [B,H,DH,S]
        out[idx] = f2bf(v);
      }
    }
  }
}

// ---- flash attention, swapped-operand 32x32 structure (m214/T12 style, DH=64):
// each wave owns 32 q-rows; S^T = mfma(K, Q) puts a full q-row of scores in-lane;
// softmax is in-register; P^T B-fragment built via pack + v_permlane32_swap_b32;
// O^T = mfma(V^T, P^T) keeps rescale lane-local. Zero LDS.
__global__ __launch_bounds__(256, 2) void attn_kernel(
    const u16* __restrict__ qh, const u16* __restrict__ kh, const u16* __restrict__ vT,
    const float* __restrict__ mask, u16* __restrict__ O) {
  const int wave = threadIdx.x >> 6, lane = threadIdx.x & 63;
  const int bh = blockIdx.x >> 4;
  const int q0 = (blockIdx.x & 15) * 128 + wave * 32;
  const int lq = lane & 31;
  const int hi = lane >> 5;
  const u16* qp = qh + (size_t)bh * SEQ * DHD;
  const u16* kp = kh + (size_t)bh * SEQ * DHD;
  const u16* vp = vT + (size_t)bh * DHD * SEQ;
  const float* mrow = mask + (size_t)(q0 + lq) * SEQ;
  const float L2E = 1.44269504088896340736f;

  short8 qf[4];
#pragma unroll
  for (int d = 0; d < 4; ++d)
    qf[d] = *reinterpret_cast<const short8*>(&qp[(size_t)(q0 + lq) * DHD + d * 16 + hi * 8]);

  f32x16 oacc[2];
#pragma unroll
  for (int e = 0; e < 16; ++e) { oacc[0][e] = 0.f; oacc[1][e] = 0.f; }
  float m2 = -INFINITY, lsum = 0.f;

  for (int kv0 = 0; kv0 < SEQ; kv0 += 64) {
    // S^T[kv][q] accumulated over d; lane holds col q=lq, rows kv=(e&3)+8*(e>>2)+4*hi (+32*h2)
    f32x16 st[2];
#pragma unroll
    for (int h2 = 0; h2 < 2; ++h2) {
      f32x16 z;
#pragma unroll
      for (int e = 0; e < 16; ++e) z[e] = 0.f;
#pragma unroll
      for (int d = 0; d < 4; ++d) {
        short8 ak = *reinterpret_cast<const short8*>(
            &kp[(size_t)(kv0 + h2 * 32 + lq) * DHD + d * 16 + hi * 8]);
        z = __builtin_amdgcn_mfma_f32_32x32x16_bf16(ak, qf[d], z, 0, 0, 0);
      }
      st[h2] = z;
    }
    // mask add (exp2 domain): p = s + mask*log2e
    float p[32];
#pragma unroll
    for (int h2 = 0; h2 < 2; ++h2)
#pragma unroll
      for (int g = 0; g < 4; ++g) {
        f32x4 mv = *reinterpret_cast<const f32x4*>(&mrow[kv0 + h2 * 32 + g * 8 + hi * 4]);
#pragma unroll
        for (int j = 0; j < 4; ++j)
          p[h2 * 16 + g * 4 + j] = fmaf(mv[j], L2E, st[h2][g * 4 + j]);
      }
    // row max: in-register tree + one cross-half exchange
    float t8[8];
#pragma unroll
    for (int i = 0; i < 8; ++i)
      t8[i] = fmaxf(fmaxf(p[i], p[i + 8]), fmaxf(p[i + 16], p[i + 24]));
#pragma unroll
    for (int i = 0; i < 4; ++i) t8[i] = fmaxf(t8[i], t8[i + 4]);
    float mt = fmaxf(fmaxf(t8[0], t8[1]), fmaxf(t8[2], t8[3]));
    mt = fmaxf(mt, __shfl_xor(mt, 32));
    const float mnew = fmaxf(m2, mt);
    const float alpha = __builtin_amdgcn_exp2f(m2 - mnew);
    m2 = mnew;
#pragma unroll
    for (int i = 0; i < 32; ++i) p[i] = __builtin_amdgcn_exp2f(p[i] - m2);
    float s8[8];
#pragma unroll
    for (int i = 0; i < 8; ++i) s8[i] = (p[i] + p[i + 8]) + (p[i + 16] + p[i + 24]);
#pragma unroll
    for (int i = 0; i < 4; ++i) s8[i] += s8[i + 4];
    float ssum = (s8[0] + s8[1]) + (s8[2] + s8[3]);
    ssum += __shfl_xor(ssum, 32);
    lsum = lsum * alpha + ssum;
#pragma unroll
    for (int e = 0; e < 16; ++e) { oacc[0][e] *= alpha; oacc[1][e] *= alpha; }

    // P^T fragments (B-operand) via pack + permlane32_swap; O^T += V^T . P^T
#pragma unroll
    for (int kb = 0; kb < 4; ++kb) {
      const int pb = (kb >> 1) * 16 + (kb & 1) * 8;
      u32 x = pack2bf(p[pb + 0], p[pb + 1]);
      u32 y = pack2bf(p[pb + 4], p[pb + 5]);
      asm volatile("v_permlane32_swap_b32 %0, %1" : "+v"(x), "+v"(y));
      u32 zz = pack2bf(p[pb + 2], p[pb + 3]);
      u32 w = pack2bf(p[pb + 6], p[pb + 7]);
      asm volatile("v_permlane32_swap_b32 %0, %1" : "+v"(zz), "+v"(w));
      union { u32 u[4]; short8 s; } bf;
      bf.u[0] = x; bf.u[1] = zz; bf.u[2] = y; bf.u[3] = w;
#pragma unroll
      for (int db = 0; db < 2; ++db) {
        short8 av = *reinterpret_cast<const short8*>(
            &vp[(size_t)(db * 32 + lq) * SEQ + kv0 + kb * 16 + hi * 8]);
        oacc[db] = __builtin_amdgcn_mfma_f32_32x32x16_bf16(av, bf.s, oacc[db], 0, 0, 0);
      }
    }
  }

  // epilogue: lane holds q = q0+lq, d = db*32 + (e&3)+8*(e>>2)+4*hi -> pack 4 consecutive d per store
  const int b = bh >> 4, h = bh & 15;
  const float inv = 1.0f / lsum;
  u16* orow = O + ((size_t)(b * SEQ + q0 + lq) * NH + h) * DHD;
#pragma unroll
  for (int db = 0; db < 2; ++db)
#pragma unroll
    for (int g = 0; g < 4; ++g) {
      union { u16 u[4]; unsigned long long ll; } pk;
#pragma unroll
      for (int j = 0; j < 4; ++j) pk.u[j] = f2bf(oacc[db][g * 4 + j] * inv);
      *reinterpret_cast<unsigned long long*>(&orow[db * 32 + g * 8 + hi * 4]) = pk.ll;
    }
}

// ---- output projection: d_out = O @ Wo^T + bo (fp32 out)
__global__ __launch_bounds__(256) void out_proj_kernel(
    const u16* __restrict__ O, const float* __restrict__ Wo, const float* __restrict__ bo,
    float* __restrict__ out) {
  __shared__ u16 As[128 * 32];
  __shared__ u16 Bs[128 * 32];
  const int m0 = blockIdx.y * 128, n0 = blockIdx.x * 128;
  f32x4 acc[4][4];
  gemm_bt_body(O, Wo, m0, n0, As, Bs, acc);

  const int lane = threadIdx.x & 63;
  const int wr = (threadIdx.x >> 7) & 1, wc = (threadIdx.x >> 6) & 1;
  const int rbase = m0 + wr * 64 + ((lane >> 4) << 2);
  const int cbase = n0 + wc * 64 + (lane & 15);
#pragma unroll
  for (int n = 0; n < 4; ++n) {
    const int col = cbase + n * 16;
    const float bvv = bo[col];
#pragma unroll
    for (int m = 0; m < 4; ++m)
#pragma unroll
      for (int r = 0; r < 4; ++r) {
        const int row = rbase + m * 16 + r;
        out[(size_t)row * FD + col] = acc[m][n][r] + bvv;
      }
  }
}

extern "C" void kernel_launch(void* const* d_in, const int* in_sizes, int n_in,
                              void* d_out, int out_size, void* d_ws, size_t ws_size,
                              hipStream_t stream) {
  (void)in_sizes; (void)n_in; (void)out_size; (void)ws_size;
  const float* Q    = (const float*)d_in[0];
  const float* K    = (const float*)d_in[1];
  const float* V    = (const float*)d_in[2];
  const float* mask = (const float*)d_in[3];
  const float* Wq   = (const float*)d_in[4];
  const float* bq   = (const float*)d_in[5];
  const float* Wk   = (const float*)d_in[6];
  const float* bk   = (const float*)d_in[7];
  const float* Wv   = (const float*)d_in[8];
  const float* bv   = (const float*)d_in[9];
  const float* Wo   = (const float*)d_in[10];
  const float* bo   = (const float*)d_in[11];
  float* out = (float*)d_out;

  u16* ws = (u16*)d_ws;
  const size_t SZ = (size_t)4096 * 1024;   // B*S*F elements
  u16* qh = ws;            // [B,H,S,DH] bf16 (pre-scaled by 0.125*log2e)
  u16* kh = qh + SZ;       // [B,H,S,DH] bf16
  u16* vT = kh + SZ;       // [B,H,DH,S] bf16
  u16* O  = vT + SZ;       // [B,S,H,DH] bf16

  dim3 gproj(FD / 128, (2 * SEQ) / 128, 3);      // (8, 32, 3)
  proj_qkv_kernel<<<gproj, 256, 0, stream>>>(Q, K, V, Wq, Wk, Wv, bq, bk, bv, qh, kh, vT);

  attn_kernel<<<dim3(512), 256, 0, stream>>>(qh, kh, vT, mask, O);

  out_proj_kernel<<<dim3(FD / 128, (2 * SEQ) / 128), 256, 0, stream>>>(O, Wo, bo, out);
}